// Round 1
// baseline (1152.765 us; speedup 1.0000x reference)
//
#include <hip/hip_runtime.h>

// SoilModelCQ: 2000-step sequential scan, 512 sites x 64 hidden buckets.
// Mapping: 1 wave per site (block=64), lane = hidden index. State in regs.
// Outputs (flat, concatenated): Q (NT,NS), C (NT,NS), S (NT,NS,NH),
// H1 (NT,NS,NH), H2 (NT,NS,NH), Qs (NT,NS,3).
//
// R1 change: replace the three 6-stage __shfl_xor butterflies (ds_swizzle,
// LDS-pipe latency ~30-120cy/stage, unhidden at 0.5 waves/SIMD) with DPP
// v_add_f32 reductions (row_shr 1/2/4/8 + row_bcast15/31, VALU latency).

constexpr int NT = 2000;
constexpr int NS = 512;
constexpr int NH = 64;
constexpr int CHUNK = 50;          // 2000 / 50 = 40 even chunks

__device__ __forceinline__ float readlane_f(float v, int k) {
    return __int_as_float(__builtin_amdgcn_readlane(__float_as_int(v), k));
}

// v += dpp_move(v, CTRL); invalid source lanes contribute 0 (bound_ctrl=1).
template<int CTRL>
__device__ __forceinline__ float dpp_add(float v) {
    int sh = __builtin_amdgcn_update_dpp(0, __float_as_int(v), CTRL, 0xf, 0xf, true);
    return v + __int_as_float(sh);
}

__global__ void __launch_bounds__(64, 1)
soil_cq_kernel(const float* __restrict__ P, const float* __restrict__ T,
               const float* __restrict__ E,
               const float* __restrict__ w,  const float* __restrict__ wk1,
               const float* __restrict__ wk2, const float* __restrict__ we1,
               const float* __restrict__ we2, const float* __restrict__ wl,
               const float* __restrict__ wo,  const float* __restrict__ wc,
               float* __restrict__ out)
{
    const int site = blockIdx.x;   // 0..511
    const int lane = threadIdx.x;  // 0..63

    // ---- per-lane parameter precompute (once per wave) ----
    float wo_l = wo[lane];
    float mx = wo_l;
    #pragma unroll
    for (int off = 32; off; off >>= 1) mx = fmaxf(mx, __shfl_xor(mx, off));
    float ex = expf(wo_l - mx);
    float ssum = ex;
    #pragma unroll
    for (int off = 32; off; off >>= 1) ssum += __shfl_xor(ssum, off);
    const float a   = ex / ssum;                       // softmax(wo)
    const float ew  = expf(w[lane]) + 1.0f;            // snow melt factor
    const float sk1 = 1.0f / (1.0f + expf(-wk1[lane]));
    const float sk2 = 1.0f / (1.0f + expf(-wk2[lane]));
    const float se1 = 1.0f / (1.0f + expf(-we1[lane]));
    const float se2 = 1.0f / (1.0f + expf(-we2[lane]));
    const float L   = expf(wl[lane]);
    const float r   = 1.0f / sk2 / (1.0f + expf(wc[lane]));
    const float ar  = a * r;

    // ---- output pointers ----
    float* Qo  = out;
    float* Co  = out + (size_t)NT * NS;
    float* So  = out + (size_t)2 * NT * NS;
    float* H1o = So  + (size_t)NT * NS * NH;
    float* H2o = H1o + (size_t)NT * NS * NH;
    float* Qso = H2o + (size_t)NT * NS * NH;

    // lanes 0..4 each own one scalar output stream
    float* optr = nullptr;
    int    ostride = 0;
    if      (lane == 0) { optr = Qo  + site;                 ostride = NS;     }
    else if (lane == 1) { optr = Co  + site;                 ostride = NS;     }
    else if (lane == 2) { optr = Qso + (size_t)site * 3;     ostride = NS * 3; }
    else if (lane == 3) { optr = Qso + (size_t)site * 3 + 1; ostride = NS * 3; }
    else if (lane == 4) { optr = Qso + (size_t)site * 3 + 2; ostride = NS * 3; }

    float s = 0.f, h1 = 0.f, h2 = 0.f;
    size_t sidx = (size_t)site * NH + lane;     // index into S/H1/H2, +NS*NH per step

    // ---- forcing prefetch: lane l holds timestep (chunk*CHUNK + l) ----
    float pv = 0.f, tv = 0.f, evv = 0.f;
    if (lane < CHUNK) {
        const size_t fb = (size_t)lane * NS + site;
        pv = P[fb]; tv = T[fb]; evv = E[fb];
    }

    for (int cb = 0; cb < NT / CHUNK; ++cb) {
        // prefetch next chunk (latency hidden behind 50 steps of compute)
        float pn = 0.f, tn = 0.f, en = 0.f;
        if (cb + 1 < NT / CHUNK && lane < CHUNK) {
            const size_t fb = ((size_t)(cb + 1) * CHUNK + lane) * NS + site;
            pn = P[fb]; tn = T[fb]; en = E[fb];
        }

        #pragma unroll 5
        for (int k = 0; k < CHUNK; ++k) {
            const float p = readlane_f(pv, k);
            const float t = readlane_f(tv, k);
            const float e = readlane_f(evv, k);

            const float tpos  = fmaxf(t, 0.f);
            const float psnow = (t < 0.f) ? p : 0.f;
            const float prain = (t > 0.f) ? p : 0.f;

            // SnowBucket
            const float smv  = tpos * ew;
            const float m    = fminf(smv, s);
            const float snew = s - m + psnow;
            const float x    = prain + m;
            // SoilBucket
            const float hh   = h1 + h2 + x;
            const float h1a  = fmaxf(hh - L, 0.f);
            const float q1   = h1a * sk1;
            const float h2a  = fminf(h1a + h2 + x, L);
            const float q2   = h2a * sk2;         // q3 == q2 in the reference
            const float e1   = e * se1;
            const float e2   = e * se2;
            const float h1n  = fmaxf(h1a - q1 - e1, 0.f);
            const float h2n  = fmaxf(h2a - q2 - e2 - q2, 0.f);

            // state outputs (coalesced: lane = contiguous h)
            So[sidx]  = snew;
            H1o[sidx] = h1n;
            H2o[sidx] = h2n;

            // reductions over 64 hidden units — DPP, VALU-latency.
            // 6 stages, three independent chains interleaved; sum lands in
            // lane 63, then broadcast via readlane.
            float v1 = q1 * a;     // -> Qs1
            float v2 = q2 * a;     // -> Qs2
            float v3 = q2 * ar;    // -> sum(q2*a*r)
            v1 = dpp_add<0x111>(v1); v2 = dpp_add<0x111>(v2); v3 = dpp_add<0x111>(v3); // row_shr:1
            v1 = dpp_add<0x112>(v1); v2 = dpp_add<0x112>(v2); v3 = dpp_add<0x112>(v3); // row_shr:2
            v1 = dpp_add<0x114>(v1); v2 = dpp_add<0x114>(v2); v3 = dpp_add<0x114>(v3); // row_shr:4
            v1 = dpp_add<0x118>(v1); v2 = dpp_add<0x118>(v2); v3 = dpp_add<0x118>(v3); // row_shr:8
            v1 = dpp_add<0x142>(v1); v2 = dpp_add<0x142>(v2); v3 = dpp_add<0x142>(v3); // row_bcast:15
            v1 = dpp_add<0x143>(v1); v2 = dpp_add<0x143>(v2); v3 = dpp_add<0x143>(v3); // row_bcast:31

            const float t1 = readlane_f(v1, 63);   // Qs1
            const float t2 = readlane_f(v2, 63);   // Qs2
            const float t3 = readlane_f(v3, 63);   // sum(q2*a*r)
            const float Qk = t1 + t2;
            const float c  = (t3 * (1.0f / NH) + 1e-5f) / (Qk + 1e-5f);

            if (lane < 5) {
                float oval = (lane == 0) ? Qk
                           : (lane == 1) ? c
                           : (lane == 2) ? t1
                           : (lane == 3) ? t2
                           : 0.f;                 // Qs[:,:,2] stays 0
                *optr = oval;
                optr += ostride;
            }

            s = snew; h1 = h1n; h2 = h2n;
            sidx += (size_t)NS * NH;
        }

        pv = pn; tv = tn; evv = en;
    }
}

extern "C" void kernel_launch(void* const* d_in, const int* in_sizes, int n_in,
                              void* d_out, int out_size, void* d_ws, size_t ws_size,
                              hipStream_t stream) {
    const float* P   = (const float*)d_in[0];
    const float* T   = (const float*)d_in[1];
    const float* E   = (const float*)d_in[2];
    const float* w   = (const float*)d_in[3];
    const float* wk1 = (const float*)d_in[4];
    const float* wk2 = (const float*)d_in[5];
    const float* we1 = (const float*)d_in[6];
    const float* we2 = (const float*)d_in[7];
    const float* wl  = (const float*)d_in[8];
    const float* wo  = (const float*)d_in[9];
    const float* wc  = (const float*)d_in[10];

    soil_cq_kernel<<<NS, 64, 0, stream>>>(P, T, E, w, wk1, wk2, we1, we2, wl,
                                          wo, wc, (float*)d_out);
}